// Round 4
// baseline (186.531 us; speedup 1.0000x reference)
//
#include <hip/hip_runtime.h>

// GMELoss3D: fused 3D Sobel edge-magnitude MSE on [2,2,128,128,128] fp32 volumes.
// R6: BARRIER-FREE rewrite — registers + ds_bpermute, no LDS staging.
//   - R4/R5 post-mortem: grid-doubling (R4) and barrier-halving (R5) both null
//     or negative => neither occupancy supply nor barrier COUNT is the limiter.
//     Measured ~3300cy per plane-window vs ~500cy VALU: the barriered-LDS
//     structure itself (vmcnt(0)+lgkmcnt(0) drain at every __syncthreads, 4-wave
//     convoy, ~2.4 blocks/CU) exposes full memory latency every window.
//   - Fix: remove the synchronization class. Wave = one 64-wide x-row.
//     x±1 neighbors via ds_bpermute (no barrier); y±1 rows loaded per-thread
//     (3x request amplification absorbed by L1/L2/L3; HBM-unique ~75MB);
//     tile-edge x-halo columns loaded by lanes 0/63 (exec-masked, pipelined).
//     Zero __syncthreads in the z-loop; each wave free-runs with a 1-plane
//     register prefetch (24 loads in flight/wave).
//   - Full unroll (18 planes) keeps pf buffer parity and mod-3 indices
//     compile-time => registers, not scratch. No launch_bounds clamp (R3).
//
// Separable decomposition: s=[1,2,1], d=[-1,0,1], e=[1,1,1].
//   C0=s_y d_x  C1=d_y s_x  C2=s_y s_x  C3=e_y d_x  C4=d_y e_x  C5=e_y s_x
//   C6=s_y e_x ; z-combines in edge_mag_half. Signs irrelevant (squared).

namespace {

constexpr int ZDIM = 128, YDIM = 128, XDIM = 128;   // (H, W, D); D contiguous
constexpr int TX = 64, TY = 4, ZC = 16;
constexpr int YX = YDIM * XDIM;           // z-plane stride (floats)
constexpr size_t CS = (size_t)ZDIM * YX;  // channel stride
constexpr float INV_N = 1.0f / 4194304.0f;

__device__ __forceinline__ float ldz(const float* p, bool ok) {
  float v = 0.0f;
  if (ok) v = *p;          // exec-masked load; v stays 0 on masked lanes
  return v;
}

__device__ __forceinline__ float bperm(int addr, float v) {
  return __int_as_float(__builtin_amdgcn_ds_bpermute(addr, __float_as_int(v)));
}

// half edge magnitude (mag / C, C=2) from 3 planes' combos (a=z-1, b=z, c=z+1)
__device__ __forceinline__ float edge_mag_half(const float* __restrict__ Ca,
                                               const float* __restrict__ Cb,
                                               const float* __restrict__ Cc) {
  const float g1  = __builtin_fmaf(2.0f, Cb[0], Ca[0] + Cc[0]);   // Sx
  const float g2  = __builtin_fmaf(2.0f, Cb[1], Ca[1] + Cc[1]);   // Sy
  const float g3  = Cc[2] - Ca[2];                                // Sz
  const float Azx = __builtin_fmaf(2.0f, Cb[3], Ca[3] + Cc[3]);   // s_z e_y d_x
  const float Azy = __builtin_fmaf(2.0f, Cb[4], Ca[4] + Cc[4]);   // s_z d_y e_x
  const float Axz = Cc[5] - Ca[5];                                // d_z e_y s_x
  const float Axy = g2 - Cb[1];                                   // e_z d_y s_x
  const float Ayx = g1 - Cb[0];                                   // e_z s_y d_x
  const float Ayz = Cc[6] - Ca[6];                                // d_z s_y e_x
  const float g4 = Azx - Azy, g5 = Azx + Azy;                     // Sd11, Sd12
  const float g6 = Axz - Axy, g7 = Axz + Axy;                     // Sd21, Sd22
  const float g8 = Ayx - Ayz, g9 = Ayx + Ayz;                     // Sd31, Sd32
  float s = __builtin_fmaf(g1, g1, 1e-12f);
  s = __builtin_fmaf(g2, g2, s); s = __builtin_fmaf(g3, g3, s);
  s = __builtin_fmaf(g4, g4, s); s = __builtin_fmaf(g5, g5, s);
  s = __builtin_fmaf(g6, g6, s); s = __builtin_fmaf(g7, g7, s);
  s = __builtin_fmaf(g8, g8, s); s = __builtin_fmaf(g9, g9, s);
  return 0.5f * sqrtf(s);
}

__global__ __launch_bounds__(256)
void gme_loss_kernel(const float* __restrict__ y,
                     const float* __restrict__ yp,
                     float* __restrict__ out) {
  const int lane = threadIdx.x;          // x within tile (0..63) == wave lane
  const int ty   = threadIdx.y;          // row within block (0..3); wave id
  const int tid  = ty * TX + lane;

  const int bx = blockIdx.x;             // bit0: x-tile, rest: y-tile
  const int x0 = (bx & 1) * TX;
  const int yy = (bx >> 1) * TY + ty;    // global row
  const int z0 = blockIdx.y * ZC;
  const int b  = blockIdx.z;

  const float* Y0 = y  + (size_t)b * 2 * CS;   // vol y, ch 0
  const float* Y1 = Y0 + CS;                   // vol y, ch 1
  const float* P0 = yp + (size_t)b * 2 * CS;   // vol yp, ch 0
  const float* P1 = P0 + CS;

  const int xg  = x0 + lane;
  const int vox = yy * XDIM + xg;
  const bool okM0 = (yy > 0);            // wave-uniform (one row per wave)
  const bool okP0 = (yy < YDIM - 1);

  // x-halo: lane0 loads column x0-1, lane63 loads column x0+64 (0 at vol edge)
  const bool left  = (lane == 0);
  const bool right = (lane == TX - 1);
  const int  hx    = left ? (x0 - 1) : (x0 + TX);
  const int  hvox  = yy * XDIM + hx;
  const bool hok0  = (left && x0 > 0) || (right && x0 + TX < XDIM);

  // hoisted bpermute byte-addresses for x-1 / x+1 (edge lanes fixed by cndmask)
  const int addrL = (lane > 0 ? lane - 1 : 0) << 2;
  const int addrR = (lane < TX - 1 ? lane + 1 : TX - 1) << 2;

  float pf[2][12];                       // prefetched raw rows (parity buffers)
  float ph[2][12];                       // prefetched halo rows
  float KY[3][7] = {}, KP[3][7] = {};    // mod-3 per-plane combo pipeline
  float acc = 0.0f;

  auto loadPlane = [&](int buf, int zc) {
    const bool zok = (unsigned)zc < (unsigned)ZDIM;
    const int  zca = zok ? zc : 0;       // address-safe clamp (loads masked)
    const int  o   = zca * YX + vox;
    const bool okC = zok, okM = zok && okM0, okP = zok && okP0;
    pf[buf][0]  = ldz(Y0 + (o - XDIM), okM);
    pf[buf][1]  = ldz(Y1 + (o - XDIM), okM);
    pf[buf][2]  = ldz(Y0 + o,          okC);
    pf[buf][3]  = ldz(Y1 + o,          okC);
    pf[buf][4]  = ldz(Y0 + (o + XDIM), okP);
    pf[buf][5]  = ldz(Y1 + (o + XDIM), okP);
    pf[buf][6]  = ldz(P0 + (o - XDIM), okM);
    pf[buf][7]  = ldz(P1 + (o - XDIM), okM);
    pf[buf][8]  = ldz(P0 + o,          okC);
    pf[buf][9]  = ldz(P1 + o,          okC);
    pf[buf][10] = ldz(P0 + (o + XDIM), okP);
    pf[buf][11] = ldz(P1 + (o + XDIM), okP);
    const int  h  = zca * YX + hvox;
    const bool hC = zok && hok0, hM = hC && okM0, hP = hC && okP0;
    ph[buf][0]  = ldz(Y0 + (h - XDIM), hM);
    ph[buf][1]  = ldz(Y1 + (h - XDIM), hM);
    ph[buf][2]  = ldz(Y0 + h,          hC);
    ph[buf][3]  = ldz(Y1 + h,          hC);
    ph[buf][4]  = ldz(Y0 + (h + XDIM), hP);
    ph[buf][5]  = ldz(Y1 + (h + XDIM), hP);
    ph[buf][6]  = ldz(P0 + (h - XDIM), hM);
    ph[buf][7]  = ldz(P1 + (h - XDIM), hM);
    ph[buf][8]  = ldz(P0 + h,          hC);
    ph[buf][9]  = ldz(P1 + h,          hC);
    ph[buf][10] = ldz(P0 + (h + XDIM), hP);
    ph[buf][11] = ldz(P1 + (h + XDIM), hP);
  };

  // one volume's 7 plane-combos from 6 raw rows + this lane's 3 halo y-combos
  auto volCombos = [&](float m0, float m1, float c0, float c1, float q0, float q1,
                       float hys, float hyd, float hye, float* __restrict__ C) {
    const float vm = m0 + m1, v0 = c0 + c1, vp = q0 + q1;   // channel sums
    const float t  = vm + vp;
    const float ys = __builtin_fmaf(2.0f, v0, t);           // s_y
    const float yd = vp - vm;                               // d_y
    const float ye = t + v0;                                // e_y
    float ysL = bperm(addrL, ys), ysR = bperm(addrR, ys);
    float ydL = bperm(addrL, yd), ydR = bperm(addrR, yd);
    float yeL = bperm(addrL, ye), yeR = bperm(addrR, ye);
    ysL = left ? hys : ysL;   ysR = right ? hys : ysR;      // tile-edge halo
    ydL = left ? hyd : ydL;   ydR = right ? hyd : ydR;
    yeL = left ? hye : yeL;   yeR = right ? hye : yeR;
    const float tS = ysL + ysR, tD = ydL + ydR, tE = yeL + yeR;
    C[0] = ysR - ysL;                           // s_y d_x
    C[2] = __builtin_fmaf(2.0f, ys, tS);        // s_y s_x
    C[6] = tS + ys;                             // s_y e_x
    C[1] = __builtin_fmaf(2.0f, yd, tD);        // d_y s_x
    C[4] = tD + yd;                             // d_y e_x
    C[3] = yeR - yeL;                           // e_y d_x
    C[5] = __builtin_fmaf(2.0f, ye, tE);        // e_y s_x
  };

  loadPlane(0, z0 - 1);                         // prologue: plane j=0

#pragma unroll
  for (int j = 0; j < ZC + 2; ++j) {            // 18 planes, zc = z0-1+j
    const int cur = j & 1;
    if (j < ZC + 1) loadPlane(cur ^ 1, z0 + j); // issue next plane's loads first

    float* Cy = KY[j % 3];
    float* Cp = KP[j % 3];
    {
      const float hvm = ph[cur][0] + ph[cur][1];
      const float hv0 = ph[cur][2] + ph[cur][3];
      const float hvp = ph[cur][4] + ph[cur][5];
      const float ht  = hvm + hvp;
      volCombos(pf[cur][0], pf[cur][1], pf[cur][2], pf[cur][3], pf[cur][4], pf[cur][5],
                __builtin_fmaf(2.0f, hv0, ht), hvp - hvm, ht + hv0, Cy);
    }
    {
      const float hvm = ph[cur][6] + ph[cur][7];
      const float hv0 = ph[cur][8] + ph[cur][9];
      const float hvp = ph[cur][10] + ph[cur][11];
      const float ht  = hvm + hvp;
      volCombos(pf[cur][6], pf[cur][7], pf[cur][8], pf[cur][9], pf[cur][10], pf[cur][11],
                __builtin_fmaf(2.0f, hv0, ht), hvp - hvm, ht + hv0, Cp);
    }
    if (j >= 2) {                               // emit output plane z0-3+j
      const float my = edge_mag_half(KY[(j + 1) % 3], KY[(j + 2) % 3], Cy);
      const float mp = edge_mag_half(KP[(j + 1) % 3], KP[(j + 2) % 3], Cp);
      const float d = my - mp;
      acc = __builtin_fmaf(d, d, acc);
    }
  }

  // ---- block reduction (only sync in the kernel) ----
  __shared__ float red[4];
#pragma unroll
  for (int off = 32; off > 0; off >>= 1) acc += __shfl_down(acc, off);
  if (lane == 0) red[ty] = acc;                 // wave id == ty (TX==64)
  __syncthreads();
  if (tid == 0) {
    const float s = (red[0] + red[1] + red[2] + red[3]) * INV_N;
    atomicAdd(out, s);
  }
}

}  // namespace

extern "C" void kernel_launch(void* const* d_in, const int* in_sizes, int n_in,
                              void* d_out, int out_size, void* d_ws, size_t ws_size,
                              hipStream_t stream) {
  const float* y  = (const float*)d_in[0];
  const float* yp = (const float*)d_in[1];
  float* out = (float*)d_out;

  // d_out is poisoned before every launch: zero via memset node (graph-capturable)
  hipMemsetAsync(out, 0, sizeof(float), stream);

  dim3 block(TX, TY, 1);                        // 256 threads = 4 waves, 1 row each
  dim3 grid((XDIM / TX) * (YDIM / TY),          // 2 x-tiles * 32 y-tiles = 64
            ZDIM / ZC,                          // 8 z-chunks
            2);                                 // batch
  gme_loss_kernel<<<grid, block, 0, stream>>>(y, yp, out);
}

// Round 5
// 121.499 us; speedup vs baseline: 1.5352x; 1.5352x over previous
//
#include <hip/hip_runtime.h>

// GMELoss3D: fused 3D Sobel edge-magnitude MSE on [2,2,128,128,128] fp32 volumes.
// R7: barrier-free dataflow (R6) with disciplined register economy.
//   - R6 post-mortem: mechanism validated (FETCH 112->91MB, 0 bank conflicts)
//     but full-18 unroll + 48 raw prefetch floats -> VGPR 256 + 27MB spills.
//   - Fixes: (1) channel-sum fused at load: 24 live floats, not 48;
//     (2) #pragma unroll 6 (lcm of parity-2 and mod-3 => all indices still
//     compile-time, rule-#20 safe) stops live-range inflation, 3x less code;
//     (3) wave-uniform y/z masks as 3 scalar branch regions per plane;
//     divergent x-halo via clamped address + v_cndmask zeroing (no exec
//     juggling per load).
//   - Wave = one 64-wide x-row; x+-1 via ds_bpermute (no barrier); y+-1 rows
//     loaded per-thread (3x request amplification absorbed by L1/L2);
//     zero __syncthreads in the z-loop.
//
// Separable decomposition: s=[1,2,1], d=[-1,0,1], e=[1,1,1], applied y-first:
//   per column: ys=s_y, yd=d_y, ye=e_y; then x-combine via lane neighbors.
//   C0=s_y d_x  C1=d_y s_x  C2=s_y s_x  C3=e_y d_x  C4=d_y e_x  C5=e_y s_x
//   C6=s_y e_x ; z-combines in edge_mag_half. Signs irrelevant (squared).

namespace {

constexpr int ZDIM = 128, YDIM = 128, XDIM = 128;   // (H, W, D); D contiguous
constexpr int TX = 64, TY = 4, ZC = 16;
constexpr int YX = YDIM * XDIM;           // z-plane stride (floats)
constexpr size_t CS = (size_t)ZDIM * YX;  // channel stride
constexpr float INV_N = 1.0f / 4194304.0f;

__device__ __forceinline__ float bperm(int addr, float v) {
  return __int_as_float(__builtin_amdgcn_ds_bpermute(addr, __float_as_int(v)));
}

// half edge magnitude (mag / C, C=2) from 3 planes' combos (a=z-1, b=z, c=z+1)
__device__ __forceinline__ float edge_mag_half(const float* __restrict__ Ca,
                                               const float* __restrict__ Cb,
                                               const float* __restrict__ Cc) {
  const float g1  = __builtin_fmaf(2.0f, Cb[0], Ca[0] + Cc[0]);   // Sx
  const float g2  = __builtin_fmaf(2.0f, Cb[1], Ca[1] + Cc[1]);   // Sy
  const float g3  = Cc[2] - Ca[2];                                // Sz
  const float Azx = __builtin_fmaf(2.0f, Cb[3], Ca[3] + Cc[3]);   // s_z e_y d_x
  const float Azy = __builtin_fmaf(2.0f, Cb[4], Ca[4] + Cc[4]);   // s_z d_y e_x
  const float Axz = Cc[5] - Ca[5];                                // d_z e_y s_x
  const float Axy = g2 - Cb[1];                                   // e_z d_y s_x
  const float Ayx = g1 - Cb[0];                                   // e_z s_y d_x
  const float Ayz = Cc[6] - Ca[6];                                // d_z s_y e_x
  const float g4 = Azx - Azy, g5 = Azx + Azy;                     // Sd11, Sd12
  const float g6 = Axz - Axy, g7 = Axz + Axy;                     // Sd21, Sd22
  const float g8 = Ayx - Ayz, g9 = Ayx + Ayz;                     // Sd31, Sd32
  float s = __builtin_fmaf(g1, g1, 1e-12f);
  s = __builtin_fmaf(g2, g2, s); s = __builtin_fmaf(g3, g3, s);
  s = __builtin_fmaf(g4, g4, s); s = __builtin_fmaf(g5, g5, s);
  s = __builtin_fmaf(g6, g6, s); s = __builtin_fmaf(g7, g7, s);
  s = __builtin_fmaf(g8, g8, s); s = __builtin_fmaf(g9, g9, s);
  return 0.5f * sqrtf(s);
}

__global__ __launch_bounds__(256)
void gme_loss_kernel(const float* __restrict__ y,
                     const float* __restrict__ yp,
                     float* __restrict__ out) {
  const int lane = threadIdx.x;          // x within tile (0..63) == wave lane
  const int ty   = threadIdx.y;          // row within block (0..3); wave id
  const int tid  = ty * TX + lane;

  const int bx = blockIdx.x;             // bit0: x-tile, rest: y-tile
  const int x0 = (bx & 1) * TX;
  const int yy = (bx >> 1) * TY + ty;    // global row
  const int z0 = blockIdx.y * ZC;
  const int b  = blockIdx.z;

  const float* Y0 = y  + (size_t)b * 2 * CS;   // vol y, ch 0
  const float* Y1 = Y0 + CS;                   // vol y, ch 1
  const float* P0 = yp + (size_t)b * 2 * CS;   // vol yp, ch 0
  const float* P1 = P0 + CS;

  const int vox = yy * XDIM + x0 + lane;
  const bool okM0 = (yy > 0);            // wave-uniform (one row per wave)
  const bool okP0 = (yy < YDIM - 1);

  // x-halo: lane0 wants column x0-1, lane63 wants x0+64. Clamped address,
  // unconditional load (mid lanes coalesce on the same clamped column),
  // zeroed by one cndmask per row-sum.
  const bool left  = (lane == 0);
  const bool right = (lane == TX - 1);
  const int  hx    = left ? (x0 - 1) : (x0 + TX);
  const bool hok   = (left && x0 > 0) || (right && x0 + TX < XDIM);
  const int  hxc   = hx < 0 ? 0 : (hx > XDIM - 1 ? XDIM - 1 : hx);
  const int  hvox  = yy * XDIM + hxc;

  // bpermute byte-addresses for x-1 / x+1 (edge lanes patched by select)
  const int addrL = (lane > 0 ? lane - 1 : 0) << 2;
  const int addrR = (lane < TX - 1 ? lane + 1 : TX - 1) << 2;

  float pr[2][6];   // channel-summed rows: [0..2]=Y (y-1,y,y+1), [3..5]=P
  float hr[2][6];   // halo channel-summed rows (0 unless edge lane)
  float KY[3][7] = {}, KP[3][7] = {};    // mod-3 per-plane combo pipeline
  float acc = 0.0f;

  auto loadSum = [&](int buf, int zc) {
    const bool zok = (unsigned)zc < (unsigned)ZDIM;
    const int  zca = zok ? zc : 0;       // address-safe clamp (loads skipped)
    const int  o   = zca * YX + vox;
    const int  h   = zca * YX + hvox;
    float ym0=0.f,ym1=0.f,pm0=0.f,pm1=0.f,hym0=0.f,hym1=0.f,hpm0=0.f,hpm1=0.f;
    if (zok && okM0) {                   // wave-uniform branch, 8 loads
      ym0 = Y0[o - XDIM]; ym1 = Y1[o - XDIM];
      pm0 = P0[o - XDIM]; pm1 = P1[o - XDIM];
      hym0 = Y0[h - XDIM]; hym1 = Y1[h - XDIM];
      hpm0 = P0[h - XDIM]; hpm1 = P1[h - XDIM];
    }
    float yc0=0.f,yc1=0.f,pc0=0.f,pc1=0.f,hyc0=0.f,hyc1=0.f,hpc0=0.f,hpc1=0.f;
    if (zok) {                           // wave-uniform branch, 8 loads
      yc0 = Y0[o]; yc1 = Y1[o]; pc0 = P0[o]; pc1 = P1[o];
      hyc0 = Y0[h]; hyc1 = Y1[h]; hpc0 = P0[h]; hpc1 = P1[h];
    }
    float yq0=0.f,yq1=0.f,pq0=0.f,pq1=0.f,hyq0=0.f,hyq1=0.f,hpq0=0.f,hpq1=0.f;
    if (zok && okP0) {                   // wave-uniform branch, 8 loads
      yq0 = Y0[o + XDIM]; yq1 = Y1[o + XDIM];
      pq0 = P0[o + XDIM]; pq1 = P1[o + XDIM];
      hyq0 = Y0[h + XDIM]; hyq1 = Y1[h + XDIM];
      hpq0 = P0[h + XDIM]; hpq1 = P1[h + XDIM];
    }
    pr[buf][0] = ym0 + ym1; pr[buf][1] = yc0 + yc1; pr[buf][2] = yq0 + yq1;
    pr[buf][3] = pm0 + pm1; pr[buf][4] = pc0 + pc1; pr[buf][5] = pq0 + pq1;
    hr[buf][0] = hok ? hym0 + hym1 : 0.f;
    hr[buf][1] = hok ? hyc0 + hyc1 : 0.f;
    hr[buf][2] = hok ? hyq0 + hyq1 : 0.f;
    hr[buf][3] = hok ? hpm0 + hpm1 : 0.f;
    hr[buf][4] = hok ? hpc0 + hpc1 : 0.f;
    hr[buf][5] = hok ? hpq0 + hpq1 : 0.f;
  };

  // one volume's 7 plane-combos from 3 row-sums + 3 halo row-sums
  auto volCombos = [&](float rm, float rc, float rp,
                       float hm, float hc, float hp, float* __restrict__ C) {
    const float t   = rm + rp;
    const float ys  = __builtin_fmaf(2.0f, rc, t);   // s_y
    const float yd  = rp - rm;                       // d_y
    const float ye  = t + rc;                        // e_y
    const float th  = hm + hp;
    const float hys = __builtin_fmaf(2.0f, hc, th);
    const float hyd = hp - hm;
    const float hye = th + hc;
    float ysL = bperm(addrL, ys), ysR = bperm(addrR, ys);
    float ydL = bperm(addrL, yd), ydR = bperm(addrR, yd);
    float yeL = bperm(addrL, ye), yeR = bperm(addrR, ye);
    ysL = left ? hys : ysL;   ysR = right ? hys : ysR;
    ydL = left ? hyd : ydL;   ydR = right ? hyd : ydR;
    yeL = left ? hye : yeL;   yeR = right ? hye : yeR;
    const float tS = ysL + ysR, tD = ydL + ydR, tE = yeL + yeR;
    C[0] = ysR - ysL;                           // s_y d_x
    C[2] = __builtin_fmaf(2.0f, ys, tS);        // s_y s_x
    C[6] = tS + ys;                             // s_y e_x
    C[1] = __builtin_fmaf(2.0f, yd, tD);        // d_y s_x
    C[4] = tD + yd;                             // d_y e_x
    C[3] = yeR - yeL;                           // e_y d_x
    C[5] = __builtin_fmaf(2.0f, ye, tE);        // e_y s_x
  };

  loadSum(0, z0 - 1);                           // prologue: plane j=0

#pragma unroll 6
  for (int j = 0; j < ZC + 2; ++j) {            // 18 planes, zc = z0-1+j
    const int cur = j & 1;
    if (j < ZC + 1) loadSum(cur ^ 1, z0 + j);   // issue next plane's loads first

    float* Cy = KY[j % 3];
    float* Cp = KP[j % 3];
    volCombos(pr[cur][0], pr[cur][1], pr[cur][2],
              hr[cur][0], hr[cur][1], hr[cur][2], Cy);
    volCombos(pr[cur][3], pr[cur][4], pr[cur][5],
              hr[cur][3], hr[cur][4], hr[cur][5], Cp);

    if (j >= 2) {                               // emit output plane z0-3+j
      const float my = edge_mag_half(KY[(j + 1) % 3], KY[(j + 2) % 3], Cy);
      const float mp = edge_mag_half(KP[(j + 1) % 3], KP[(j + 2) % 3], Cp);
      const float d = my - mp;
      acc = __builtin_fmaf(d, d, acc);
    }
  }

  // ---- block reduction (only sync in the kernel) ----
  __shared__ float red[4];
#pragma unroll
  for (int off = 32; off > 0; off >>= 1) acc += __shfl_down(acc, off);
  if (lane == 0) red[ty] = acc;                 // wave id == ty (TX==64)
  __syncthreads();
  if (tid == 0) {
    const float s = (red[0] + red[1] + red[2] + red[3]) * INV_N;
    atomicAdd(out, s);
  }
}

}  // namespace

extern "C" void kernel_launch(void* const* d_in, const int* in_sizes, int n_in,
                              void* d_out, int out_size, void* d_ws, size_t ws_size,
                              hipStream_t stream) {
  const float* y  = (const float*)d_in[0];
  const float* yp = (const float*)d_in[1];
  float* out = (float*)d_out;

  // d_out is poisoned before every launch: zero via memset node (graph-capturable)
  hipMemsetAsync(out, 0, sizeof(float), stream);

  dim3 block(TX, TY, 1);                        // 256 threads = 4 waves, 1 row each
  dim3 grid((XDIM / TX) * (YDIM / TY),          // 2 x-tiles * 32 y-tiles = 64
            ZDIM / ZC,                          // 8 z-chunks
            2);                                 // batch
  gme_loss_kernel<<<grid, block, 0, stream>>>(y, yp, out);
}

// Round 6
// 117.228 us; speedup vs baseline: 1.5912x; 1.0364x over previous
//
#include <hip/hip_runtime.h>

// GMELoss3D: fused 3D Sobel edge-magnitude MSE on [2,2,128,128,128] fp32 volumes.
// R8: restore the prefetch overlap R7 accidentally destroyed.
//   - R7 post-mortem: FETCH 81MB / 0 conflicts / no spills all good, BUT
//     loadSum did channel-sum arithmetic ON the loaded values in the same
//     iteration -> compiler must vmcnt-drain before every plane's compute ->
//     full load latency exposed per plane (~500cy stall of ~930cy period).
//   - Fix 1: stage RAW load destinations (pf[2][12]); all arithmetic deferred
//     to consume time next iteration -> reads of pf[cur] need only
//     vmcnt(12), the 12 plane-(j+1) loads stay in flight across compute.
//   - Fix 2: drop halo-column loads (were 12 broadcast loads + 12 selects per
//     plane, half of all VMEM instr). Overlapped tiles instead: 3 waves cover
//     128 columns, each emits lanes 1..62; out-of-range lanes zeroed via one
//     hoisted xok mask; invalid outputs gated from acc by eok.
//   - Wave = one x-row, x+-1 via ds_bpermute, zero __syncthreads in z-loop,
//     unroll 6 (lcm of parity-2/mod-3; all indices compile-time, rule #20).
//
// Separable decomposition: s=[1,2,1], d=[-1,0,1], e=[1,1,1], y-first:
//   C0=s_y d_x  C1=d_y s_x  C2=s_y s_x  C3=e_y d_x  C4=d_y e_x  C5=e_y s_x
//   C6=s_y e_x ; z-combines in edge_mag_half. Signs irrelevant (squared).

namespace {

constexpr int ZDIM = 128, YDIM = 128, XDIM = 128;   // (H, W, D); D contiguous
constexpr int TX = 64, TY = 4, ZC = 16;
constexpr int OTW = 62;                   // output columns per overlapped tile
constexpr int NXT = 3;                    // x-tiles: ceil(128/62)
constexpr int YX = YDIM * XDIM;           // z-plane stride (floats)
constexpr size_t CS = (size_t)ZDIM * YX;  // channel stride
constexpr float INV_N = 1.0f / 4194304.0f;

__device__ __forceinline__ float bperm(int addr, float v) {
  return __int_as_float(__builtin_amdgcn_ds_bpermute(addr, __float_as_int(v)));
}

// half edge magnitude (mag / C, C=2) from 3 planes' combos (a=z-1, b=z, c=z+1)
__device__ __forceinline__ float edge_mag_half(const float* __restrict__ Ca,
                                               const float* __restrict__ Cb,
                                               const float* __restrict__ Cc) {
  const float g1  = __builtin_fmaf(2.0f, Cb[0], Ca[0] + Cc[0]);   // Sx
  const float g2  = __builtin_fmaf(2.0f, Cb[1], Ca[1] + Cc[1]);   // Sy
  const float g3  = Cc[2] - Ca[2];                                // Sz
  const float Azx = __builtin_fmaf(2.0f, Cb[3], Ca[3] + Cc[3]);   // s_z e_y d_x
  const float Azy = __builtin_fmaf(2.0f, Cb[4], Ca[4] + Cc[4]);   // s_z d_y e_x
  const float Axz = Cc[5] - Ca[5];                                // d_z e_y s_x
  const float Axy = g2 - Cb[1];                                   // e_z d_y s_x
  const float Ayx = g1 - Cb[0];                                   // e_z s_y d_x
  const float Ayz = Cc[6] - Ca[6];                                // d_z s_y e_x
  const float g4 = Azx - Azy, g5 = Azx + Azy;                     // Sd11, Sd12
  const float g6 = Axz - Axy, g7 = Axz + Axy;                     // Sd21, Sd22
  const float g8 = Ayx - Ayz, g9 = Ayx + Ayz;                     // Sd31, Sd32
  float s = __builtin_fmaf(g1, g1, 1e-12f);
  s = __builtin_fmaf(g2, g2, s); s = __builtin_fmaf(g3, g3, s);
  s = __builtin_fmaf(g4, g4, s); s = __builtin_fmaf(g5, g5, s);
  s = __builtin_fmaf(g6, g6, s); s = __builtin_fmaf(g7, g7, s);
  s = __builtin_fmaf(g8, g8, s); s = __builtin_fmaf(g9, g9, s);
  return 0.5f * sqrtf(s);
}

__global__ __launch_bounds__(256)
void gme_loss_kernel(const float* __restrict__ y,
                     const float* __restrict__ yp,
                     float* __restrict__ out) {
  const int lane = threadIdx.x;          // lane in wave == x within tile
  const int ty   = threadIdx.y;          // row within block (0..3); wave id
  const int tid  = ty * TX + lane;

  const int bx = blockIdx.x;             // 3 x-tiles * 32 y-tiles
  const int t  = bx % NXT;
  const int yt = bx / NXT;
  const int yy = yt * TY + ty;           // global row (wave-uniform)
  const int z0 = blockIdx.y * ZC;
  const int b  = blockIdx.z;

  const float* Y0 = y  + (size_t)b * 2 * CS;   // vol y, ch 0
  const float* Y1 = Y0 + CS;                   // vol y, ch 1
  const float* P0 = yp + (size_t)b * 2 * CS;   // vol yp, ch 0
  const float* P1 = P0 + CS;

  // overlapped tile: loads columns X0..X0+63, emits outputs at lanes 1..62
  const int  X0  = OTW * t - 1;
  const int  xg  = X0 + lane;
  const int  xgc = xg < 0 ? 0 : (xg > XDIM - 1 ? XDIM - 1 : xg);
  const bool xok = (unsigned)xg < (unsigned)XDIM;    // zero-pad mask
  const bool eok = xok && (lane >= 1) && (lane <= OTW);  // emit mask

  const int vox = yy * XDIM + xgc;
  const bool okM0 = (yy > 0);            // wave-uniform
  const bool okP0 = (yy < YDIM - 1);

  // bpermute byte-addresses for x-1 / x+1 (clamped; edge lanes never emit)
  const int addrL = (lane > 0 ? lane - 1 : 0) << 2;
  const int addrR = (lane < TX - 1 ? lane + 1 : TX - 1) << 2;

  // RAW prefetch buffers — no arithmetic on these until next iteration.
  // layout: [0]Y0m [1]Y1m [2]P0m [3]P1m [4]Y0c [5]Y1c [6]P0c [7]P1c
  //         [8]Y0p [9]Y1p [10]P0p [11]P1p    (m/c/p = rows y-1 / y / y+1)
  float pf[2][12];
  float KY[3][7] = {}, KP[3][7] = {};    // mod-3 per-plane combo pipeline
  float acc = 0.0f;

  auto loadRaw = [&](int buf, int zc) {
    const bool zok = (unsigned)zc < (unsigned)ZDIM;
    const int  zca = zok ? zc : 0;       // address-safe clamp (loads skipped)
    const int  o   = zca * YX + vox;
    float a0=0.f,a1=0.f,a2=0.f,a3=0.f;
    if (zok && okM0) {                   // wave-uniform branch, 4 loads
      a0 = Y0[o - XDIM]; a1 = Y1[o - XDIM];
      a2 = P0[o - XDIM]; a3 = P1[o - XDIM];
    }
    float b0=0.f,b1=0.f,b2=0.f,b3=0.f;
    if (zok) {                           // wave-uniform branch, 4 loads
      b0 = Y0[o]; b1 = Y1[o]; b2 = P0[o]; b3 = P1[o];
    }
    float c0=0.f,c1=0.f,c2=0.f,c3=0.f;
    if (zok && okP0) {                   // wave-uniform branch, 4 loads
      c0 = Y0[o + XDIM]; c1 = Y1[o + XDIM];
      c2 = P0[o + XDIM]; c3 = P1[o + XDIM];
    }
    pf[buf][0] = a0;  pf[buf][1] = a1;  pf[buf][2]  = a2;  pf[buf][3]  = a3;
    pf[buf][4] = b0;  pf[buf][5] = b1;  pf[buf][6]  = b2;  pf[buf][7]  = b3;
    pf[buf][8] = c0;  pf[buf][9] = c1;  pf[buf][10] = c2;  pf[buf][11] = c3;
  };

  // one volume's 7 plane-combos from 3 channel-summed rows (masked by xok)
  auto volCombos = [&](float sm, float sc, float sp, float* __restrict__ C) {
    const float tt = sm + sp;
    float ys = __builtin_fmaf(2.0f, sc, tt);   // s_y
    float yd = sp - sm;                        // d_y
    float ye = tt + sc;                        // e_y
    ys = xok ? ys : 0.0f;
    yd = xok ? yd : 0.0f;
    ye = xok ? ye : 0.0f;
    const float ysL = bperm(addrL, ys), ysR = bperm(addrR, ys);
    const float ydL = bperm(addrL, yd), ydR = bperm(addrR, yd);
    const float yeL = bperm(addrL, ye), yeR = bperm(addrR, ye);
    const float tS = ysL + ysR, tD = ydL + ydR, tE = yeL + yeR;
    C[0] = ysR - ysL;                           // s_y d_x
    C[2] = __builtin_fmaf(2.0f, ys, tS);        // s_y s_x
    C[6] = tS + ys;                             // s_y e_x
    C[1] = __builtin_fmaf(2.0f, yd, tD);        // d_y s_x
    C[4] = tD + yd;                             // d_y e_x
    C[3] = yeR - yeL;                           // e_y d_x
    C[5] = __builtin_fmaf(2.0f, ye, tE);        // e_y s_x
  };

  loadRaw(0, z0 - 1);                           // prologue: plane j=0

#pragma unroll 6
  for (int j = 0; j < ZC + 2; ++j) {            // 18 planes, zc = z0-1+j
    const int cur = j & 1;
    if (j < ZC + 1) loadRaw(cur ^ 1, z0 + j);   // issue next plane's 12 loads

    // consume pf[cur] (loaded LAST iteration -> only vmcnt(12) wait needed)
    const float* q = pf[cur];
    const float sYm = q[0] + q[1],  sPm = q[2] + q[3];
    const float sYc = q[4] + q[5],  sPc = q[6] + q[7];
    const float sYp = q[8] + q[9],  sPp = q[10] + q[11];

    float* Cy = KY[j % 3];
    float* Cp = KP[j % 3];
    volCombos(sYm, sYc, sYp, Cy);
    volCombos(sPm, sPc, sPp, Cp);

    if (j >= 2) {                               // emit output plane z0-3+j
      const float my = edge_mag_half(KY[(j + 1) % 3], KY[(j + 2) % 3], Cy);
      const float mp = edge_mag_half(KP[(j + 1) % 3], KP[(j + 2) % 3], Cp);
      float d = my - mp;
      d = eok ? d : 0.0f;
      acc = __builtin_fmaf(d, d, acc);
    }
  }

  // ---- block reduction (only sync in the kernel) ----
  __shared__ float red[4];
#pragma unroll
  for (int off = 32; off > 0; off >>= 1) acc += __shfl_down(acc, off);
  if (lane == 0) red[ty] = acc;                 // wave id == ty (TX==64)
  __syncthreads();
  if (tid == 0) {
    const float s = (red[0] + red[1] + red[2] + red[3]) * INV_N;
    atomicAdd(out, s);
  }
}

}  // namespace

extern "C" void kernel_launch(void* const* d_in, const int* in_sizes, int n_in,
                              void* d_out, int out_size, void* d_ws, size_t ws_size,
                              hipStream_t stream) {
  const float* y  = (const float*)d_in[0];
  const float* yp = (const float*)d_in[1];
  float* out = (float*)d_out;

  // d_out is poisoned before every launch: zero via memset node (graph-capturable)
  hipMemsetAsync(out, 0, sizeof(float), stream);

  dim3 block(TX, TY, 1);                        // 256 threads = 4 waves, 1 row each
  dim3 grid(NXT * (YDIM / TY),                  // 3 x-tiles * 32 y-tiles = 96
            ZDIM / ZC,                          // 8 z-chunks
            2);                                 // batch  => 1536 blocks
  gme_loss_kernel<<<grid, block, 0, stream>>>(y, yp, out);
}